// Round 4
// baseline (4363.029 us; speedup 1.0000x reference)
//
#include <hip/hip_runtime.h>
#include <hip/hip_bf16.h>

// SCAE forward on MI355X — f16 split-MFMA (Ootomo 3-product) pipeline.
//   v = h + l/2048 (f16 h,l; subnormal-guarded)  =>
//   A@B = Ah@Bh + (Ah@Bl + Al@Bh)/2048   (drop 2^-22 term)
// All GEMMs are A[M][K] x BT[N][K] row-major (m97 pattern):
//   G0: approx = x @ W_enc       A=x_hl,        BT=W_encT_hl,   C=f32 +bias2
//   G1: virtT  = W_encT @ uWdT   A=W_encT_hl,   BT=up_W_dec_hl, C=f16 h/l planes, mask in epilogue
//   G2: approx+= up_feats @ virt A=up_feats_hl, BT=virtT_hl,    C=f32 +=
// Then exact radix top-k (ties->lowest index), relu, sparse decode.
//
// R4: double-buffered LDS (BK 64->32, h/l packed per 128B row), STAGE(next)
// issued before compute(cur), ONE barrier per K-step -> staging overlaps MFMA.
// The compiler's vmcnt(0) drain at the barrier lands after a full MFMA phase.

#define D_DIM 768
#define F_DIM 8192

typedef _Float16 f16;
typedef _Float16 f16x8 __attribute__((ext_vector_type(8)));
typedef float f32x4 __attribute__((ext_vector_type(4)));

#define BMN 128
#define BUFB 32768    // one K-tile: A plane 16KB + B plane 16KB
#define PLNB 16384    // 128 rows x 128B (row = [h k0..31 | l k0..31], XOR-8 swizzled)

__device__ inline void split_f32(float v, f16& h, f16& l) {
    float hf = (float)(f16)v;
    if (__builtin_fabsf(hf) < 6.1035156e-5f) hf = 0.f;   // keep h MFMA-normal
    h = (f16)hf;
    l = (f16)((v - hf) * 2048.0f);
}

// MODE 0: C = comb + bias[col]          (f32)
// MODE 1: Vh/Vl = split(comb * mask)    (f16 planes, ld F_DIM)
// MODE 2: C += comb                     (f32)
template<int MODE>
__global__ __launch_bounds__(256, 2)
void mfma_gemm(const f16* __restrict__ Ahp, const f16* __restrict__ Alp, int lda,
               const f16* __restrict__ Bhp, const f16* __restrict__ Blp, int ldb,
               float* __restrict__ C, int ldc,
               f16* __restrict__ Vh, f16* __restrict__ Vl,
               const float* __restrict__ bias,
               const unsigned char* __restrict__ conn, int upIdx,
               const int* __restrict__ flagp,
               int K, int fdBase)
{
    __shared__ char lds[2 * BUFB];   // double-buffered K-tile
    const int tid = threadIdx.x;
    const int bm = blockIdx.y * BMN;
    const int bn = blockIdx.x * BMN;
    const int w  = tid >> 6;
    const int l  = tid & 63;
    const int wr = (w >> 1) * 64;   // wave row origin
    const int wc = (w & 1) * 64;    // wave col origin

    // Staging: 2048 chunks of 16B per K-tile, 8 per thread (c = tid + 256j).
    // chunk c: plane p=c>>10 (0=A,1=B), row r=(c>>3)&127, phys slot sp=c&7.
    // logical slot = sp ^ (r&7); logical 0-3 = h-plane k-slot, 4-7 = l-plane.
    // LDS dest is linear (c*16); the source is pre-swizzled (rule #21).
    const char* gsrc[8];
    #pragma unroll
    for (int j = 0; j < 8; ++j) {
        const int c = tid + 256 * j;
        const int p = c >> 10;
        const int q = c & 1023;
        const int r = q >> 3;
        const int sp = q & 7;
        const int slog = sp ^ (r & 7);
        const f16* hb = p ? Bhp : Ahp;
        const f16* lb = p ? Blp : Alp;
        const int ld  = p ? ldb : lda;
        const int row0 = p ? bn : bm;
        const f16* base = (slog < 4) ? hb : lb;
        gsrc[j] = (const char*)(base + (size_t)(row0 + r) * ld + (slog & 3) * 8);
    }

    #define STAGE(BUFSEL)                                                     \
        _Pragma("unroll")                                                     \
        for (int j = 0; j < 8; ++j) {                                         \
            __builtin_amdgcn_global_load_lds(                                 \
                (const __attribute__((address_space(1))) void*)gsrc[j],       \
                (__attribute__((address_space(3))) void*)                     \
                    (lds + (BUFSEL) * BUFB + (tid + 256 * j) * 16),           \
                16, 0, 0);                                                    \
            gsrc[j] += 64;   /* advance 32 f16 along k */                     \
        }

    f32x4 accH[4][4], accM[4][4];
    const f32x4 zero = {0.f, 0.f, 0.f, 0.f};
    #pragma unroll
    for (int a = 0; a < 4; ++a)
        #pragma unroll
        for (int b = 0; b < 4; ++b) { accH[a][b] = zero; accM[a][b] = zero; }

    const int steps = K >> 5;
    const int fr = l & 15;
    const int ks = l >> 4;          // k-slot 0..3

    STAGE(0);
    int cur = 0;
    for (int t = 0; t < steps; ++t) {
        // loads for buf[cur] were issued one phase ago -> near-zero stall here
        asm volatile("s_waitcnt vmcnt(0)" ::: "memory");
        __syncthreads();
        if (t + 1 < steps) STAGE(cur ^ 1);

        const char* Lb = lds + cur * BUFB;
        f16x8 ah[4], bh[4];
        #pragma unroll
        for (int mf = 0; mf < 4; ++mf) {
            const int r = wr + mf * 16 + fr;
            ah[mf] = *(const f16x8*)(Lb + r * 128 + ((ks ^ (r & 7)) * 16));
        }
        #pragma unroll
        for (int nf = 0; nf < 4; ++nf) {
            const int r = wc + nf * 16 + fr;
            bh[nf] = *(const f16x8*)(Lb + PLNB + r * 128 + ((ks ^ (r & 7)) * 16));
        }
        #pragma unroll
        for (int nf = 0; nf < 4; ++nf)
            #pragma unroll
            for (int mf = 0; mf < 4; ++mf)
                accH[mf][nf] = __builtin_amdgcn_mfma_f32_16x16x32_f16(
                    ah[mf], bh[nf], accH[mf][nf], 0, 0, 0);
        #pragma unroll
        for (int nf = 0; nf < 4; ++nf) {
            const int r = wc + nf * 16 + fr;
            const f16x8 bl = *(const f16x8*)(Lb + PLNB + r * 128 +
                                             (((4 + ks) ^ (r & 7)) * 16));
            #pragma unroll
            for (int mf = 0; mf < 4; ++mf)
                accM[mf][nf] = __builtin_amdgcn_mfma_f32_16x16x32_f16(
                    ah[mf], bl, accM[mf][nf], 0, 0, 0);
        }
        #pragma unroll
        for (int mf = 0; mf < 4; ++mf) {
            const int r = wr + mf * 16 + fr;
            const f16x8 al = *(const f16x8*)(Lb + r * 128 +
                                             (((4 + ks) ^ (r & 7)) * 16));
            #pragma unroll
            for (int nf = 0; nf < 4; ++nf)
                accM[mf][nf] = __builtin_amdgcn_mfma_f32_16x16x32_f16(
                    al, bh[nf], accM[mf][nf], 0, 0, 0);
        }
        cur ^= 1;
    }
    #undef STAGE

    const float MS = 4.8828125e-4f;   // 1/2048
    const int flag = (MODE == 1) ? *flagp : 0;

    #pragma unroll
    for (int mf = 0; mf < 4; ++mf) {
        const int row0 = wr + mf * 16 + (l >> 4) * 4;   // local row of reg 0
        #pragma unroll
        for (int nf = 0; nf < 4; ++nf) {
            const int col = wc + nf * 16 + (l & 15);
            float v[4];
            #pragma unroll
            for (int rr = 0; rr < 4; ++rr)
                v[rr] = accH[mf][nf][rr] + accM[mf][nf][rr] * MS;

            if (MODE == 0) {
                const float bb = bias[bn + col];
                #pragma unroll
                for (int rr = 0; rr < 4; ++rr)
                    C[(size_t)(bm + row0 + rr) * ldc + (bn + col)] = v[rr] + bb;
            } else if (MODE == 2) {
                #pragma unroll
                for (int rr = 0; rr < 4; ++rr) {
                    float* cp = &C[(size_t)(bm + row0 + rr) * ldc + (bn + col)];
                    *cp = *cp + v[rr];
                }
            } else {
                const size_t fu = (size_t)(bn + col);
                const size_t fd0 = (size_t)(fdBase + bm + row0);
                int m[4];
                if (flag == 1) {
                    const int4 mm = *(const int4*)((const int*)conn +
                        (size_t)upIdx * F_DIM * F_DIM + fu * F_DIM + fd0);
                    m[0] = mm.x; m[1] = mm.y; m[2] = mm.z; m[3] = mm.w;
                } else if (flag == 0) {
                    const uchar4 mm = *(const uchar4*)(conn +
                        (size_t)upIdx * F_DIM * F_DIM + fu * F_DIM + fd0);
                    m[0] = mm.x; m[1] = mm.y; m[2] = mm.z; m[3] = mm.w;
                } else if (flag == 2) {
                    const long long* pp = (const long long*)conn +
                        (size_t)upIdx * F_DIM * F_DIM + fu * F_DIM + fd0;
                    m[0] = (int)pp[0]; m[1] = (int)pp[1];
                    m[2] = (int)pp[2]; m[3] = (int)pp[3];
                } else {
                    const float4 mm = *(const float4*)((const float*)conn +
                        (size_t)upIdx * F_DIM * F_DIM + fu * F_DIM + fd0);
                    m[0] = mm.x != 0.f; m[1] = mm.y != 0.f;
                    m[2] = mm.z != 0.f; m[3] = mm.w != 0.f;
                }
                #pragma unroll
                for (int rr = 0; rr < 4; ++rr) {
                    const float vv = m[rr] ? v[rr] : 0.f;
                    f16 hh, ll;
                    split_f32(vv, hh, ll);
                    const size_t o = (size_t)(bm + row0 + rr) * F_DIM + fu;
                    Vh[o] = hh; Vl[o] = ll;
                }
            }
        }
    }
}

// elementwise split: 8 elems/thread, coalesced
__global__ __launch_bounds__(256)
void split_kernel(const float* __restrict__ src, f16* __restrict__ h,
                  f16* __restrict__ l, size_t n)
{
    const size_t e = ((size_t)blockIdx.x * 256 + threadIdx.x) * 8;
    if (e >= n) return;
    const float4 a = *(const float4*)(src + e);
    const float4 b = *(const float4*)(src + e + 4);
    f16 hv[8], lv[8];
    const float s[8] = {a.x, a.y, a.z, a.w, b.x, b.y, b.z, b.w};
    #pragma unroll
    for (int i = 0; i < 8; ++i) split_f32(s[i], hv[i], lv[i]);
    *(f16x8*)(h + e) = *(const f16x8*)hv;
    *(f16x8*)(l + e) = *(const f16x8*)lv;
}

// W_enc [768][8192] -> W_encT planes [8192][768]; reads coalesced along f
__global__ __launch_bounds__(256)
void transpose_split_kernel(const float* __restrict__ W,
                            f16* __restrict__ th, f16* __restrict__ tl)
{
    const int f = blockIdx.x * 256 + threadIdx.x;
    for (int dc = 0; dc < D_DIM / 8; ++dc) {
        f16 hv[8], lv[8];
        #pragma unroll
        for (int j = 0; j < 8; ++j)
            split_f32(W[(size_t)(dc * 8 + j) * F_DIM + f], hv[j], lv[j]);
        *(f16x8*)(th + (size_t)f * D_DIM + dc * 8) = *(const f16x8*)hv;
        *(f16x8*)(tl + (size_t)f * D_DIM + dc * 8) = *(const f16x8*)lv;
    }
}

// conn_mask storage-layout detection: 0=u8, 1=i32, 2=i64, 3=f32
__global__ void detect_kernel(const int* __restrict__ conn, int* __restrict__ flag)
{
    __shared__ int not01, notf01, odd_nz;
    if (threadIdx.x == 0) { not01 = 0; notf01 = 0; odd_nz = 0; }
    __syncthreads();
    const int4 v = ((const int4*)conn)[threadIdx.x];
    const unsigned a[4] = {(unsigned)v.x, (unsigned)v.y,
                           (unsigned)v.z, (unsigned)v.w};
    int l_not01 = 0, l_notf = 0;
    #pragma unroll
    for (int i = 0; i < 4; ++i) {
        if (a[i] > 1u) l_not01 = 1;
        if (a[i] != 0u && a[i] != 0x3F800000u) l_notf = 1;
    }
    if (l_not01) atomicOr(&not01, 1);
    if (l_notf)  atomicOr(&notf01, 1);
    if (a[1] | a[3]) atomicOr(&odd_nz, 1);
    __syncthreads();
    if (threadIdx.x == 0) {
        int f;
        if (!not01)        f = odd_nz ? 1 : 2;
        else if (!notf01)  f = 3;
        else               f = 0;
        *flag = f;
    }
}

__global__ void bias2_kernel(const float* __restrict__ W_enc,
                             const float* __restrict__ b_enc,
                             const float* __restrict__ up_b_dec,
                             int nup, float* __restrict__ bias2)
{
    const int g = blockIdx.x * 256 + threadIdx.x;
    if (g >= F_DIM) return;
    float s = b_enc[g];
    for (int d = 0; d < D_DIM; ++d) {
        float ub = 0.f;
        for (int i = 0; i < nup; ++i) ub += up_b_dec[i * D_DIM + d];
        s = __builtin_fmaf(ub, W_enc[(size_t)d * F_DIM + g], s);
    }
    bias2[g] = s;
}

// exact radix top-k (ties -> lowest index), relu, sparse decode
__global__ __launch_bounds__(256)
void topk_decode_kernel(const float* __restrict__ approx,
                        const float* __restrict__ W_dec,
                        const float* __restrict__ b_dec,
                        const int* __restrict__ kptr,
                        float* __restrict__ out)
{
    __shared__ unsigned keys[F_DIM];
    __shared__ int hist[256];
    __shared__ unsigned sh_prefix;
    __shared__ int sh_need;
    __shared__ int sel_cnt, eq_cnt;
    __shared__ int sidx[128];
    __shared__ float sval[128];
    __shared__ int eqidx[1024];

    const int tid = threadIdx.x;
    const int row = blockIdx.x;
    const int k = *kptr;
    const float* arow = approx + (size_t)row * F_DIM;

    for (int j = tid; j < F_DIM; j += 256) {
        unsigned u = __float_as_uint(arow[j]);
        u = (u & 0x80000000u) ? ~u : (u | 0x80000000u);
        keys[j] = u;
    }
    if (tid == 0) { sh_prefix = 0u; sh_need = k; sel_cnt = 0; eq_cnt = 0; }
    __syncthreads();

    for (int shift = 24; shift >= 0; shift -= 8) {
        if (tid < 256) hist[tid] = 0;
        __syncthreads();
        const unsigned pfx = sh_prefix;
        for (int j = tid; j < F_DIM; j += 256) {
            const unsigned u = keys[j];
            const bool match =
                (shift == 24) || ((u >> (shift + 8)) == (pfx >> (shift + 8)));
            if (match) atomicAdd(&hist[(u >> shift) & 255], 1);
        }
        __syncthreads();
        if (tid == 0) {
            int need = sh_need;
            for (int b = 255; b >= 0; --b) {
                const int c = hist[b];
                if (c >= need) {
                    sh_prefix = pfx | ((unsigned)b << shift);
                    sh_need = need;
                    break;
                }
                need -= c;
            }
        }
        __syncthreads();
    }
    const unsigned T = sh_prefix;
    const int r = sh_need;

    for (int j = tid; j < F_DIM; j += 256) {
        const unsigned u = keys[j];
        if (u > T) {
            const int p = atomicAdd(&sel_cnt, 1);
            sidx[p] = j;
        } else if (u == T) {
            const int p = atomicAdd(&eq_cnt, 1);
            if (p < 1024) eqidx[p] = j;
        }
    }
    __syncthreads();

    if (tid == 0) {
        const int m = sel_cnt;
        const int e = eq_cnt < 1024 ? eq_cnt : 1024;
        for (int t2 = 0; t2 < r; ++t2) {
            int best = 0x7FFFFFFF, bi = -1;
            for (int q = 0; q < e; ++q) {
                const int v = eqidx[q];
                if (v >= 0 && v < best) { best = v; bi = q; }
            }
            if (bi >= 0) { eqidx[bi] = -1; sidx[m + t2] = best; }
        }
        sel_cnt = m + r;
        const int n = sel_cnt;
        for (int a2 = 1; a2 < n; ++a2) {
            const int v = sidx[a2];
            int b2 = a2 - 1;
            while (b2 >= 0 && sidx[b2] > v) { sidx[b2 + 1] = sidx[b2]; --b2; }
            sidx[b2 + 1] = v;
        }
    }
    __syncthreads();

    const int total = sel_cnt;
    for (int j = tid; j < total; j += 256) {
        const float v = arow[sidx[j]];
        sval[j] = v > 0.f ? v : 0.f;
    }
    __syncthreads();

    float acc0 = b_dec[tid];
    float acc1 = b_dec[tid + 256];
    float acc2 = b_dec[tid + 512];
    for (int j = 0; j < total; ++j) {
        const float v = sval[j];
        const float* wv = W_dec + (size_t)sidx[j] * D_DIM;
        acc0 = __builtin_fmaf(v, wv[tid],       acc0);
        acc1 = __builtin_fmaf(v, wv[tid + 256], acc1);
        acc2 = __builtin_fmaf(v, wv[tid + 512], acc2);
    }
    float* orow = out + (size_t)row * D_DIM;
    orow[tid] = acc0;
    orow[tid + 256] = acc1;
    orow[tid + 512] = acc2;
}

extern "C" void kernel_launch(void* const* d_in, const int* in_sizes, int n_in,
                              void* d_out, int out_size, void* d_ws, size_t ws_size,
                              hipStream_t stream)
{
    const float* x         = (const float*)d_in[1];
    const float* up_feats  = (const float*)d_in[2];
    const float* W_enc     = (const float*)d_in[3];
    const float* b_enc     = (const float*)d_in[4];
    const float* W_dec     = (const float*)d_in[5];
    const float* b_dec     = (const float*)d_in[6];
    const float* up_W_dec  = (const float*)d_in[7];
    const float* up_b_dec  = (const float*)d_in[8];
    const unsigned char* conn = (const unsigned char*)d_in[9];
    const int* kptr        = (const int*)d_in[10];

    const int BS  = in_sizes[1] / D_DIM;    // 2048
    const int NUP = in_sizes[8] / D_DIM;    // 3

    char* ws = (char*)d_ws;
    size_t off = 0;
    auto alloc = [&](size_t bytes) -> char* {
        off = (off + 255) & ~(size_t)255;
        char* p = ws + off; off += bytes; return p;
    };
    float* approx = (float*)alloc((size_t)BS * F_DIM * 4);
    float* bias2  = (float*)alloc(F_DIM * 4);
    int*   flag   = (int*)alloc(256);
    f16* xh  = (f16*)alloc((size_t)BS * D_DIM * 2);
    f16* xl  = (f16*)alloc((size_t)BS * D_DIM * 2);
    f16* Wth = (f16*)alloc((size_t)F_DIM * D_DIM * 2);
    f16* Wtl = (f16*)alloc((size_t)F_DIM * D_DIM * 2);
    f16* uwdh = (f16*)alloc((size_t)NUP * F_DIM * D_DIM * 2);
    f16* uwdl = (f16*)alloc((size_t)NUP * F_DIM * D_DIM * 2);
    f16* ufh = (f16*)alloc((size_t)NUP * BS * F_DIM * 2);
    f16* ufl = (f16*)alloc((size_t)NUP * BS * F_DIM * 2);

    off = (off + 255) & ~(size_t)255;
    const size_t rem = (ws_size > off) ? ws_size - off : 0;
    int FC = (int)((rem / ((size_t)F_DIM * 2 * 2)) / 128 * 128);
    if (FC > F_DIM) FC = F_DIM;
    if (FC < 128) FC = 128;   // assume ws is large enough (observed ~3.2GB)
    f16* vh = (f16*)alloc((size_t)FC * F_DIM * 2);
    f16* vl = (f16*)alloc((size_t)FC * F_DIM * 2);

    detect_kernel<<<1, 256, 0, stream>>>((const int*)conn, flag);
    bias2_kernel<<<F_DIM / 256, 256, 0, stream>>>(W_enc, b_enc, up_b_dec, NUP, bias2);

    split_kernel<<<(unsigned)((size_t)BS * D_DIM / 2048), 256, 0, stream>>>(
        x, xh, xl, (size_t)BS * D_DIM);
    split_kernel<<<(unsigned)((size_t)NUP * F_DIM * D_DIM / 2048), 256, 0, stream>>>(
        up_W_dec, uwdh, uwdl, (size_t)NUP * F_DIM * D_DIM);
    split_kernel<<<(unsigned)((size_t)NUP * BS * F_DIM / 2048), 256, 0, stream>>>(
        up_feats, ufh, ufl, (size_t)NUP * BS * F_DIM);
    transpose_split_kernel<<<F_DIM / 256, 256, 0, stream>>>(W_enc, Wth, Wtl);

    // G0: approx = x @ W_enc + bias2
    mfma_gemm<0><<<dim3(F_DIM / BMN, BS / BMN), 256, 0, stream>>>(
        xh, xl, D_DIM, Wth, Wtl, D_DIM,
        approx, F_DIM, nullptr, nullptr, bias2,
        nullptr, 0, flag, D_DIM, 0);

    for (int i = 0; i < NUP; ++i) {
        for (int fc = 0; fc < F_DIM; fc += FC) {
            const int chunk = (F_DIM - fc) < FC ? (F_DIM - fc) : FC;
            // G1: virtT[fd in chunk][fu] = (W_encT @ up_W_dec[i]^T) * maskT
            mfma_gemm<1><<<dim3(F_DIM / BMN, chunk / BMN), 256, 0, stream>>>(
                Wth + (size_t)fc * D_DIM, Wtl + (size_t)fc * D_DIM, D_DIM,
                uwdh + (size_t)i * F_DIM * D_DIM, uwdl + (size_t)i * F_DIM * D_DIM, D_DIM,
                nullptr, 0, vh, vl, nullptr,
                conn, i, flag, D_DIM, fc);
            // G2: approx[:, fc:fc+chunk] += up_feats[i] @ virt (K = full fu range)
            mfma_gemm<2><<<dim3(chunk / BMN, BS / BMN), 256, 0, stream>>>(
                ufh + (size_t)i * BS * F_DIM, ufl + (size_t)i * BS * F_DIM, F_DIM,
                vh, vl, F_DIM,
                approx + fc, F_DIM, nullptr, nullptr, nullptr,
                nullptr, 0, flag, F_DIM, 0);
        }
    }

    topk_decode_kernel<<<BS, 256, 0, stream>>>(
        approx, W_dec, b_dec, kptr, (float*)d_out);
}

// Round 5
// 3883.244 us; speedup vs baseline: 1.1236x; 1.1236x over previous
//
#include <hip/hip_runtime.h>
#include <hip/hip_bf16.h>

// SCAE forward on MI355X — f16 split-MFMA (Ootomo 3-product) pipeline.
//   v = h + l/2048 (f16 h,l; subnormal-guarded)  =>
//   A@B = Ah@Bh + (Ah@Bl + Al@Bh)/2048   (drop 2^-22 term)
// All GEMMs are A[M][K] x BT[N][K] row-major (m97 pattern):
//   G0: approx = x @ W_enc       A=x_pk,   BT=W_encT_pk,   C=f32 +bias2
//   G1: virtT  = W_encT @ uWdT   A=Wt_pk,  BT=up_W_dec_pk, C=packed f16, mask in epilogue
//   G2: approx+= up_feats @ virt A=uf_pk,  BT=virtT_pk,    C=f32 +=
// Then exact radix top-k (ties->lowest index), relu, sparse decode.
//
// R5: PACKED h/l layout — each row = [h k0..31 | l k0..31 | h k32..63 | ...]
// so a BK=32 K-step reads 128B contiguous per row (fixes R4's 2x FETCH_SIZE
// L2-sharing regression) while keeping R4's double-buffered LDS with
// STAGE(next) overlapping the 48 register-MFMAs (one barrier per K-step).

#define D_DIM 768
#define F_DIM 8192

typedef _Float16 f16;
typedef _Float16 f16x8 __attribute__((ext_vector_type(8)));
typedef float f32x4 __attribute__((ext_vector_type(4)));

#define BMN 128
#define BUFB 32768    // one K-tile: A 16KB + B 16KB (128 rows x 128B each)
#define PLNB 16384    // per-matrix region: 128 rows x 128B ([h|l] packed, XOR-8 swizzled)

__device__ inline void split_f32(float v, f16& h, f16& l) {
    float hf = (float)(f16)v;
    if (__builtin_fabsf(hf) < 6.1035156e-5f) hf = 0.f;   // keep h MFMA-normal
    h = (f16)hf;
    l = (f16)((v - hf) * 2048.0f);
}

// MODE 0: C = comb + bias[col]             (f32)
// MODE 1: Vp = packed_split(comb * mask)   (f16, row = 2*F_DIM elems)
// MODE 2: C += comb                        (f32)
template<int MODE>
__global__ __launch_bounds__(256, 2)
void mfma_gemm(const f16* __restrict__ Ap,     // packed, row stride 2K f16
               const f16* __restrict__ Bp,     // packed BT, row stride 2K f16
               float* __restrict__ C, int ldc,
               f16* __restrict__ Vp,
               const float* __restrict__ bias,
               const unsigned char* __restrict__ conn, int upIdx,
               const int* __restrict__ flagp,
               int K, int fdBase)
{
    __shared__ char lds[2 * BUFB];   // double-buffered K-tile
    const int tid = threadIdx.x;
    const int bm = blockIdx.y * BMN;
    const int bn = blockIdx.x * BMN;
    const int w  = tid >> 6;
    const int l  = tid & 63;
    const int wr = (w >> 1) * 64;   // wave row origin
    const int wc = (w & 1) * 64;    // wave col origin

    // Staging: 2048 chunks of 16B per K-tile, 8/thread (c = tid + 256j).
    // chunk c: matrix p=c>>10 (0=A,1=B), row r=(c>>3)&127, phys slot sp=c&7.
    // logical slot = sp ^ (r&7) (XOR-8, involution); row source bytes are
    // CONTIGUOUS 128B = [h k-slots 0..3 | l k-slots 0..3]. LDS dest linear.
    const char* gsrc[8];
    #pragma unroll
    for (int j = 0; j < 8; ++j) {
        const int c = tid + 256 * j;
        const int p = c >> 10;
        const int q = c & 1023;
        const int r = q >> 3;
        const int sp = q & 7;
        const int slog = sp ^ (r & 7);
        const f16* base = p ? Bp : Ap;
        const int row0 = p ? bn : bm;
        gsrc[j] = (const char*)base + (size_t)(row0 + r) * ((size_t)K * 4)
                  + slog * 16;
    }

    #define STAGE(BUFSEL)                                                     \
        _Pragma("unroll")                                                     \
        for (int j = 0; j < 8; ++j) {                                         \
            __builtin_amdgcn_global_load_lds(                                 \
                (const __attribute__((address_space(1))) void*)gsrc[j],       \
                (__attribute__((address_space(3))) void*)                     \
                    (lds + (BUFSEL) * BUFB + (tid + 256 * j) * 16),           \
                16, 0, 0);                                                    \
            gsrc[j] += 128;   /* next 32-k packed block */                    \
        }

    f32x4 accH[4][4], accM[4][4];
    const f32x4 zero = {0.f, 0.f, 0.f, 0.f};
    #pragma unroll
    for (int a = 0; a < 4; ++a)
        #pragma unroll
        for (int b = 0; b < 4; ++b) { accH[a][b] = zero; accM[a][b] = zero; }

    const int steps = K >> 5;
    const int fr = l & 15;
    const int ks = l >> 4;          // k-slot 0..3

    STAGE(0);
    int cur = 0;
    for (int t = 0; t < steps; ++t) {
        // buf[cur]'s loads were issued one phase ago (hidden under MFMAs)
        asm volatile("s_waitcnt vmcnt(0)" ::: "memory");
        __syncthreads();
        if (t + 1 < steps) STAGE(cur ^ 1);

        const char* Lb = lds + cur * BUFB;
        f16x8 ah[4], bh[4];
        #pragma unroll
        for (int mf = 0; mf < 4; ++mf) {
            const int r = wr + mf * 16 + fr;
            ah[mf] = *(const f16x8*)(Lb + r * 128 + ((ks ^ (r & 7)) * 16));
        }
        #pragma unroll
        for (int nf = 0; nf < 4; ++nf) {
            const int r = wc + nf * 16 + fr;
            bh[nf] = *(const f16x8*)(Lb + PLNB + r * 128 + ((ks ^ (r & 7)) * 16));
        }
        #pragma unroll
        for (int nf = 0; nf < 4; ++nf)
            #pragma unroll
            for (int mf = 0; mf < 4; ++mf)
                accH[mf][nf] = __builtin_amdgcn_mfma_f32_16x16x32_f16(
                    ah[mf], bh[nf], accH[mf][nf], 0, 0, 0);
        #pragma unroll
        for (int nf = 0; nf < 4; ++nf) {
            const int r = wc + nf * 16 + fr;
            const f16x8 bl = *(const f16x8*)(Lb + PLNB + r * 128 +
                                             (((4 + ks) ^ (r & 7)) * 16));
            #pragma unroll
            for (int mf = 0; mf < 4; ++mf)
                accM[mf][nf] = __builtin_amdgcn_mfma_f32_16x16x32_f16(
                    ah[mf], bl, accM[mf][nf], 0, 0, 0);
        }
        #pragma unroll
        for (int mf = 0; mf < 4; ++mf) {
            const int r = wr + mf * 16 + fr;
            const f16x8 al = *(const f16x8*)(Lb + r * 128 +
                                             (((4 + ks) ^ (r & 7)) * 16));
            #pragma unroll
            for (int nf = 0; nf < 4; ++nf)
                accM[mf][nf] = __builtin_amdgcn_mfma_f32_16x16x32_f16(
                    al, bh[nf], accM[mf][nf], 0, 0, 0);
        }
        cur ^= 1;
    }
    #undef STAGE

    const float MS = 4.8828125e-4f;   // 1/2048
    const int flag = (MODE == 1) ? *flagp : 0;

    #pragma unroll
    for (int mf = 0; mf < 4; ++mf) {
        const int row0 = wr + mf * 16 + (l >> 4) * 4;   // local row of reg 0
        #pragma unroll
        for (int nf = 0; nf < 4; ++nf) {
            const int col = wc + nf * 16 + (l & 15);
            float v[4];
            #pragma unroll
            for (int rr = 0; rr < 4; ++rr)
                v[rr] = accH[mf][nf][rr] + accM[mf][nf][rr] * MS;

            if (MODE == 0) {
                const float bb = bias[bn + col];
                #pragma unroll
                for (int rr = 0; rr < 4; ++rr)
                    C[(size_t)(bm + row0 + rr) * ldc + (bn + col)] = v[rr] + bb;
            } else if (MODE == 2) {
                #pragma unroll
                for (int rr = 0; rr < 4; ++rr) {
                    float* cp = &C[(size_t)(bm + row0 + rr) * ldc + (bn + col)];
                    *cp = *cp + v[rr];
                }
            } else {
                const size_t fu = (size_t)(bn + col);
                const size_t fd0 = (size_t)(fdBase + bm + row0);
                int m[4];
                if (flag == 1) {
                    const int4 mm = *(const int4*)((const int*)conn +
                        (size_t)upIdx * F_DIM * F_DIM + fu * F_DIM + fd0);
                    m[0] = mm.x; m[1] = mm.y; m[2] = mm.z; m[3] = mm.w;
                } else if (flag == 0) {
                    const uchar4 mm = *(const uchar4*)(conn +
                        (size_t)upIdx * F_DIM * F_DIM + fu * F_DIM + fd0);
                    m[0] = mm.x; m[1] = mm.y; m[2] = mm.z; m[3] = mm.w;
                } else if (flag == 2) {
                    const long long* pp = (const long long*)conn +
                        (size_t)upIdx * F_DIM * F_DIM + fu * F_DIM + fd0;
                    m[0] = (int)pp[0]; m[1] = (int)pp[1];
                    m[2] = (int)pp[2]; m[3] = (int)pp[3];
                } else {
                    const float4 mm = *(const float4*)((const float*)conn +
                        (size_t)upIdx * F_DIM * F_DIM + fu * F_DIM + fd0);
                    m[0] = mm.x != 0.f; m[1] = mm.y != 0.f;
                    m[2] = mm.z != 0.f; m[3] = mm.w != 0.f;
                }
                // packed write: row fd, k=fu -> fd*2F + (fu>>5)*64 + (fu&31)
                const size_t kblk = (fu >> 5) * 64 + (fu & 31);
                #pragma unroll
                for (int rr = 0; rr < 4; ++rr) {
                    const float vv = m[rr] ? v[rr] : 0.f;
                    f16 hh, ll;
                    split_f32(vv, hh, ll);
                    const size_t o = (size_t)(bm + row0 + rr) * (2 * F_DIM) + kblk;
                    Vp[o] = hh; Vp[o + 32] = ll;
                }
            }
        }
    }
}

// elementwise split into packed layout: row r of K -> 2K f16, blocks of
// [32 h | 32 l]. 8 contiguous k per thread (stay within one 32-block).
__global__ __launch_bounds__(256)
void split_kernel(const float* __restrict__ src, f16* __restrict__ dst,
                  size_t n, int K)
{
    const size_t e = ((size_t)blockIdx.x * 256 + threadIdx.x) * 8;
    if (e >= n) return;
    const size_t r = e / (size_t)K;
    const int k = (int)(e - r * (size_t)K);
    const float4 a = *(const float4*)(src + e);
    const float4 b = *(const float4*)(src + e + 4);
    f16 hv[8], lv[8];
    const float s[8] = {a.x, a.y, a.z, a.w, b.x, b.y, b.z, b.w};
    #pragma unroll
    for (int i = 0; i < 8; ++i) split_f32(s[i], hv[i], lv[i]);
    const size_t base = r * (size_t)(2 * K) + (size_t)((k >> 5) * 64 + (k & 31));
    *(f16x8*)(dst + base)      = *(const f16x8*)hv;
    *(f16x8*)(dst + base + 32) = *(const f16x8*)lv;
}

// W_enc [768][8192] -> packed W_encT rows f (K=768); reads coalesced along f
__global__ __launch_bounds__(256)
void transpose_split_kernel(const float* __restrict__ W, f16* __restrict__ dst)
{
    const int f = blockIdx.x * 256 + threadIdx.x;
    for (int dc = 0; dc < D_DIM / 8; ++dc) {
        const int k = dc * 8;
        f16 hv[8], lv[8];
        #pragma unroll
        for (int j = 0; j < 8; ++j)
            split_f32(W[(size_t)(k + j) * F_DIM + f], hv[j], lv[j]);
        const size_t base = (size_t)f * (2 * D_DIM) + (k >> 5) * 64 + (k & 31);
        *(f16x8*)(dst + base)      = *(const f16x8*)hv;
        *(f16x8*)(dst + base + 32) = *(const f16x8*)lv;
    }
}

// conn_mask storage-layout detection: 0=u8, 1=i32, 2=i64, 3=f32
__global__ void detect_kernel(const int* __restrict__ conn, int* __restrict__ flag)
{
    __shared__ int not01, notf01, odd_nz;
    if (threadIdx.x == 0) { not01 = 0; notf01 = 0; odd_nz = 0; }
    __syncthreads();
    const int4 v = ((const int4*)conn)[threadIdx.x];
    const unsigned a[4] = {(unsigned)v.x, (unsigned)v.y,
                           (unsigned)v.z, (unsigned)v.w};
    int l_not01 = 0, l_notf = 0;
    #pragma unroll
    for (int i = 0; i < 4; ++i) {
        if (a[i] > 1u) l_not01 = 1;
        if (a[i] != 0u && a[i] != 0x3F800000u) l_notf = 1;
    }
    if (l_not01) atomicOr(&not01, 1);
    if (l_notf)  atomicOr(&notf01, 1);
    if (a[1] | a[3]) atomicOr(&odd_nz, 1);
    __syncthreads();
    if (threadIdx.x == 0) {
        int f;
        if (!not01)        f = odd_nz ? 1 : 2;
        else if (!notf01)  f = 3;
        else               f = 0;
        *flag = f;
    }
}

__global__ void bias2_kernel(const float* __restrict__ W_enc,
                             const float* __restrict__ b_enc,
                             const float* __restrict__ up_b_dec,
                             int nup, float* __restrict__ bias2)
{
    const int g = blockIdx.x * 256 + threadIdx.x;
    if (g >= F_DIM) return;
    float s = b_enc[g];
    for (int d = 0; d < D_DIM; ++d) {
        float ub = 0.f;
        for (int i = 0; i < nup; ++i) ub += up_b_dec[i * D_DIM + d];
        s = __builtin_fmaf(ub, W_enc[(size_t)d * F_DIM + g], s);
    }
    bias2[g] = s;
}

// exact radix top-k (ties -> lowest index), relu, sparse decode
__global__ __launch_bounds__(256)
void topk_decode_kernel(const float* __restrict__ approx,
                        const float* __restrict__ W_dec,
                        const float* __restrict__ b_dec,
                        const int* __restrict__ kptr,
                        float* __restrict__ out)
{
    __shared__ unsigned keys[F_DIM];
    __shared__ int hist[256];
    __shared__ unsigned sh_prefix;
    __shared__ int sh_need;
    __shared__ int sel_cnt, eq_cnt;
    __shared__ int sidx[128];
    __shared__ float sval[128];
    __shared__ int eqidx[1024];

    const int tid = threadIdx.x;
    const int row = blockIdx.x;
    const int k = *kptr;
    const float* arow = approx + (size_t)row * F_DIM;

    for (int j = tid; j < F_DIM; j += 256) {
        unsigned u = __float_as_uint(arow[j]);
        u = (u & 0x80000000u) ? ~u : (u | 0x80000000u);
        keys[j] = u;
    }
    if (tid == 0) { sh_prefix = 0u; sh_need = k; sel_cnt = 0; eq_cnt = 0; }
    __syncthreads();

    for (int shift = 24; shift >= 0; shift -= 8) {
        if (tid < 256) hist[tid] = 0;
        __syncthreads();
        const unsigned pfx = sh_prefix;
        for (int j = tid; j < F_DIM; j += 256) {
            const unsigned u = keys[j];
            const bool match =
                (shift == 24) || ((u >> (shift + 8)) == (pfx >> (shift + 8)));
            if (match) atomicAdd(&hist[(u >> shift) & 255], 1);
        }
        __syncthreads();
        if (tid == 0) {
            int need = sh_need;
            for (int b = 255; b >= 0; --b) {
                const int c = hist[b];
                if (c >= need) {
                    sh_prefix = pfx | ((unsigned)b << shift);
                    sh_need = need;
                    break;
                }
                need -= c;
            }
        }
        __syncthreads();
    }
    const unsigned T = sh_prefix;
    const int r = sh_need;

    for (int j = tid; j < F_DIM; j += 256) {
        const unsigned u = keys[j];
        if (u > T) {
            const int p = atomicAdd(&sel_cnt, 1);
            sidx[p] = j;
        } else if (u == T) {
            const int p = atomicAdd(&eq_cnt, 1);
            if (p < 1024) eqidx[p] = j;
        }
    }
    __syncthreads();

    if (tid == 0) {
        const int m = sel_cnt;
        const int e = eq_cnt < 1024 ? eq_cnt : 1024;
        for (int t2 = 0; t2 < r; ++t2) {
            int best = 0x7FFFFFFF, bi = -1;
            for (int q = 0; q < e; ++q) {
                const int v = eqidx[q];
                if (v >= 0 && v < best) { best = v; bi = q; }
            }
            if (bi >= 0) { eqidx[bi] = -1; sidx[m + t2] = best; }
        }
        sel_cnt = m + r;
        const int n = sel_cnt;
        for (int a2 = 1; a2 < n; ++a2) {
            const int v = sidx[a2];
            int b2 = a2 - 1;
            while (b2 >= 0 && sidx[b2] > v) { sidx[b2 + 1] = sidx[b2]; --b2; }
            sidx[b2 + 1] = v;
        }
    }
    __syncthreads();

    const int total = sel_cnt;
    for (int j = tid; j < total; j += 256) {
        const float v = arow[sidx[j]];
        sval[j] = v > 0.f ? v : 0.f;
    }
    __syncthreads();

    float acc0 = b_dec[tid];
    float acc1 = b_dec[tid + 256];
    float acc2 = b_dec[tid + 512];
    for (int j = 0; j < total; ++j) {
        const float v = sval[j];
        const float* wv = W_dec + (size_t)sidx[j] * D_DIM;
        acc0 = __builtin_fmaf(v, wv[tid],       acc0);
        acc1 = __builtin_fmaf(v, wv[tid + 256], acc1);
        acc2 = __builtin_fmaf(v, wv[tid + 512], acc2);
    }
    float* orow = out + (size_t)row * D_DIM;
    orow[tid] = acc0;
    orow[tid + 256] = acc1;
    orow[tid + 512] = acc2;
}

extern "C" void kernel_launch(void* const* d_in, const int* in_sizes, int n_in,
                              void* d_out, int out_size, void* d_ws, size_t ws_size,
                              hipStream_t stream)
{
    const float* x         = (const float*)d_in[1];
    const float* up_feats  = (const float*)d_in[2];
    const float* W_enc     = (const float*)d_in[3];
    const float* b_enc     = (const float*)d_in[4];
    const float* W_dec     = (const float*)d_in[5];
    const float* b_dec     = (const float*)d_in[6];
    const float* up_W_dec  = (const float*)d_in[7];
    const float* up_b_dec  = (const float*)d_in[8];
    const unsigned char* conn = (const unsigned char*)d_in[9];
    const int* kptr        = (const int*)d_in[10];

    const int BS  = in_sizes[1] / D_DIM;    // 2048
    const int NUP = in_sizes[8] / D_DIM;    // 3

    char* ws = (char*)d_ws;
    size_t off = 0;
    auto alloc = [&](size_t bytes) -> char* {
        off = (off + 255) & ~(size_t)255;
        char* p = ws + off; off += bytes; return p;
    };
    float* approx = (float*)alloc((size_t)BS * F_DIM * 4);
    float* bias2  = (float*)alloc(F_DIM * 4);
    int*   flag   = (int*)alloc(256);
    // packed arrays: logical n elems -> 2n f16 = 4n bytes
    f16* xp   = (f16*)alloc((size_t)BS * D_DIM * 4);
    f16* Wtp  = (f16*)alloc((size_t)F_DIM * D_DIM * 4);
    f16* uwdp = (f16*)alloc((size_t)NUP * F_DIM * D_DIM * 4);
    f16* ufp  = (f16*)alloc((size_t)NUP * BS * F_DIM * 4);

    off = (off + 255) & ~(size_t)255;
    const size_t rem = (ws_size > off) ? ws_size - off : 0;
    int FC = (int)((rem / ((size_t)F_DIM * 4)) / 128 * 128);
    if (FC > F_DIM) FC = F_DIM;
    if (FC < 128) FC = 128;   // ws observed ~3.2GB -> FC = 8192
    f16* vp = (f16*)alloc((size_t)FC * F_DIM * 4);

    detect_kernel<<<1, 256, 0, stream>>>((const int*)conn, flag);
    bias2_kernel<<<F_DIM / 256, 256, 0, stream>>>(W_enc, b_enc, up_b_dec, NUP, bias2);

    split_kernel<<<(unsigned)((size_t)BS * D_DIM / 2048), 256, 0, stream>>>(
        x, xp, (size_t)BS * D_DIM, D_DIM);
    split_kernel<<<(unsigned)((size_t)NUP * F_DIM * D_DIM / 2048), 256, 0, stream>>>(
        up_W_dec, uwdp, (size_t)NUP * F_DIM * D_DIM, D_DIM);
    split_kernel<<<(unsigned)((size_t)NUP * BS * F_DIM / 2048), 256, 0, stream>>>(
        up_feats, ufp, (size_t)NUP * BS * F_DIM, F_DIM);
    transpose_split_kernel<<<F_DIM / 256, 256, 0, stream>>>(W_enc, Wtp);

    // G0: approx = x @ W_enc + bias2
    mfma_gemm<0><<<dim3(F_DIM / BMN, BS / BMN), 256, 0, stream>>>(
        xp, Wtp, approx, F_DIM, nullptr, bias2,
        nullptr, 0, flag, D_DIM, 0);

    for (int i = 0; i < NUP; ++i) {
        for (int fc = 0; fc < F_DIM; fc += FC) {
            const int chunk = (F_DIM - fc) < FC ? (F_DIM - fc) : FC;
            // G1: virtT[fd in chunk][fu] = (W_encT @ up_W_dec[i]^T) * maskT
            mfma_gemm<1><<<dim3(F_DIM / BMN, chunk / BMN), 256, 0, stream>>>(
                Wtp + (size_t)fc * (2 * D_DIM),
                uwdp + (size_t)i * F_DIM * (2 * D_DIM),
                nullptr, 0, vp, nullptr,
                conn, i, flag, D_DIM, fc);
            // G2: approx[:, fc:fc+chunk] += up_feats[i] @ virt  (K = 8192 fu)
            mfma_gemm<2><<<dim3(chunk / BMN, BS / BMN), 256, 0, stream>>>(
                ufp + (size_t)i * BS * (2 * F_DIM),
                vp,
                approx + fc, F_DIM, nullptr, nullptr,
                nullptr, 0, flag, F_DIM, 0);
        }
    }

    topk_decode_kernel<<<BS, 256, 0, stream>>>(
        approx, W_dec, b_dec, kptr, (float*)d_out);
}

// Round 6
// 3786.405 us; speedup vs baseline: 1.1523x; 1.0256x over previous
//
#include <hip/hip_runtime.h>
#include <hip/hip_bf16.h>

// SCAE forward on MI355X — f16 split-MFMA (Ootomo 3-product) pipeline.
//   v = h + l/2048 (f16 h,l; subnormal-guarded)  =>
//   A@B = Ah@Bh + (Ah@Bl + Al@Bh)/2048   (drop 2^-22 term)
// All GEMMs are A[M][K] x BT[N][K] row-major (m97 pattern):
//   G0: approx = x @ W_enc       A=x_pk,   BT=W_encT_pk,   C=f32 +bias2
//   G1: virtT  = W_encT @ uWdT   A=Wt_pk,  BT=up_W_dec_pk, C=packed f16, mask in epilogue
//   G2: approx+= up_feats @ virt A=uf_pk,  BT=virtT_pk,    C=f32 +=
// Then exact radix top-k (ties->lowest index), relu, sparse decode.
//
// R6 (vs R5): MFMA-pipe-bound analysis (19.4 cyc/SIMD per 16x16x32, LDS has
// 3.6x headroom). Cut critical-path VALU + phase the loop:
//   - hoisted, loop-invariant LDS read offsets (XOR-swizzle arithmetic once)
//   - h-fragment reads first -> H-MFMAs start at lgkmcnt(8), l-reads overlap
//   - STAGE(next) issued between the two read groups
//   - s_setprio(1) around both MFMA clusters (phase-split makes T5 live)

#define D_DIM 768
#define F_DIM 8192

typedef _Float16 f16;
typedef _Float16 f16x8 __attribute__((ext_vector_type(8)));
typedef float f32x4 __attribute__((ext_vector_type(4)));

#define BMN 128
#define BUFB 32768    // one K-tile: A 16KB + B 16KB (128 rows x 128B each)
#define PLNB 16384    // per-matrix region: 128 rows x 128B ([h|l] packed, XOR-8 swizzled)

__device__ inline void split_f32(float v, f16& h, f16& l) {
    float hf = (float)(f16)v;
    if (__builtin_fabsf(hf) < 6.1035156e-5f) hf = 0.f;   // keep h MFMA-normal
    h = (f16)hf;
    l = (f16)((v - hf) * 2048.0f);
}

// MODE 0: C = comb + bias[col]             (f32)
// MODE 1: Vp = packed_split(comb * mask)   (f16, row = 2*F_DIM elems)
// MODE 2: C += comb                        (f32)
template<int MODE>
__global__ __launch_bounds__(256, 2)
void mfma_gemm(const f16* __restrict__ Ap,     // packed, row stride 2K f16
               const f16* __restrict__ Bp,     // packed BT, row stride 2K f16
               float* __restrict__ C, int ldc,
               f16* __restrict__ Vp,
               const float* __restrict__ bias,
               const unsigned char* __restrict__ conn, int upIdx,
               const int* __restrict__ flagp,
               int K, int fdBase)
{
    __shared__ char lds[2 * BUFB];   // double-buffered K-tile
    const int tid = threadIdx.x;
    const int bm = blockIdx.y * BMN;
    const int bn = blockIdx.x * BMN;
    const int w  = tid >> 6;
    const int l  = tid & 63;
    const int wr = (w >> 1) * 64;   // wave row origin
    const int wc = (w & 1) * 64;    // wave col origin

    // Staging: 2048 chunks of 16B per K-tile, 8/thread (c = tid + 256j).
    // chunk c: matrix p=c>>10 (0=A,1=B), row r=(c>>3)&127, phys slot sp=c&7.
    // logical slot = sp ^ (r&7) (XOR-8, involution); row source bytes are
    // CONTIGUOUS 128B = [h k-slots 0..3 | l k-slots 0..3]. LDS dest linear.
    const char* gsrc[8];
    #pragma unroll
    for (int j = 0; j < 8; ++j) {
        const int c = tid + 256 * j;
        const int p = c >> 10;
        const int q = c & 1023;
        const int r = q >> 3;
        const int sp = q & 7;
        const int slog = sp ^ (r & 7);
        const f16* base = p ? Bp : Ap;
        const int row0 = p ? bn : bm;
        gsrc[j] = (const char*)base + (size_t)(row0 + r) * ((size_t)K * 4)
                  + slog * 16;
    }

    #define STAGE(BUFSEL)                                                     \
        _Pragma("unroll")                                                     \
        for (int j = 0; j < 8; ++j) {                                         \
            __builtin_amdgcn_global_load_lds(                                 \
                (const __attribute__((address_space(1))) void*)gsrc[j],       \
                (__attribute__((address_space(3))) void*)                     \
                    (lds + (BUFSEL) * BUFB + (tid + 256 * j) * 16),           \
                16, 0, 0);                                                    \
            gsrc[j] += 128;   /* next 32-k packed block */                    \
        }

    f32x4 accH[4][4], accM[4][4];
    const f32x4 zero = {0.f, 0.f, 0.f, 0.f};
    #pragma unroll
    for (int a = 0; a < 4; ++a)
        #pragma unroll
        for (int b = 0; b < 4; ++b) { accH[a][b] = zero; accM[a][b] = zero; }

    const int steps = K >> 5;
    const int fr = l & 15;
    const int ks = l >> 4;          // k-slot 0..3

    // Hoisted loop-invariant LDS read byte-offsets (XOR-swizzle math ONCE).
    int offAH[4], offBH[4], offAL[4], offBL[4];
    #pragma unroll
    for (int f = 0; f < 4; ++f) {
        const int ra = wr + f * 16 + fr;
        const int rb = wc + f * 16 + fr;
        offAH[f] = ra * 128 + ((ks ^ (ra & 7)) * 16);
        offAL[f] = ra * 128 + (((4 + ks) ^ (ra & 7)) * 16);
        offBH[f] = PLNB + rb * 128 + ((ks ^ (rb & 7)) * 16);
        offBL[f] = PLNB + rb * 128 + (((4 + ks) ^ (rb & 7)) * 16);
    }

    STAGE(0);
    int cur = 0;
    for (int t = 0; t < steps; ++t) {
        // buf[cur]'s loads were issued one phase ago (hidden under MFMAs)
        asm volatile("s_waitcnt vmcnt(0)" ::: "memory");
        __syncthreads();

        const char* Lb = lds + cur * BUFB;
        // ---- read h-fragments (8 reads) ----
        f16x8 ah[4], bh[4];
        #pragma unroll
        for (int mf = 0; mf < 4; ++mf) ah[mf] = *(const f16x8*)(Lb + offAH[mf]);
        #pragma unroll
        for (int nf = 0; nf < 4; ++nf) bh[nf] = *(const f16x8*)(Lb + offBH[nf]);

        // ---- stage next tile (drained at next iter's top) ----
        if (t + 1 < steps) STAGE(cur ^ 1);

        // ---- read l-fragments (8 reads; overlap H-MFMAs via lgkmcnt(8)) ----
        f16x8 al[4], bl[4];
        #pragma unroll
        for (int nf = 0; nf < 4; ++nf) bl[nf] = *(const f16x8*)(Lb + offBL[nf]);
        #pragma unroll
        for (int mf = 0; mf < 4; ++mf) al[mf] = *(const f16x8*)(Lb + offAL[mf]);

        // ---- H phase: 16 MFMAs ----
        __builtin_amdgcn_s_setprio(1);
        #pragma unroll
        for (int nf = 0; nf < 4; ++nf)
            #pragma unroll
            for (int mf = 0; mf < 4; ++mf)
                accH[mf][nf] = __builtin_amdgcn_mfma_f32_16x16x32_f16(
                    ah[mf], bh[nf], accH[mf][nf], 0, 0, 0);
        __builtin_amdgcn_s_setprio(0);

        // ---- M phase: 32 MFMAs ----
        __builtin_amdgcn_s_setprio(1);
        #pragma unroll
        for (int nf = 0; nf < 4; ++nf)
            #pragma unroll
            for (int mf = 0; mf < 4; ++mf)
                accM[mf][nf] = __builtin_amdgcn_mfma_f32_16x16x32_f16(
                    ah[mf], bl[nf], accM[mf][nf], 0, 0, 0);
        #pragma unroll
        for (int mf = 0; mf < 4; ++mf)
            #pragma unroll
            for (int nf = 0; nf < 4; ++nf)
                accM[mf][nf] = __builtin_amdgcn_mfma_f32_16x16x32_f16(
                    al[mf], bh[nf], accM[mf][nf], 0, 0, 0);
        __builtin_amdgcn_s_setprio(0);

        cur ^= 1;
    }
    #undef STAGE

    const float MS = 4.8828125e-4f;   // 1/2048
    const int flag = (MODE == 1) ? *flagp : 0;

    #pragma unroll
    for (int mf = 0; mf < 4; ++mf) {
        const int row0 = wr + mf * 16 + (l >> 4) * 4;   // local row of reg 0
        #pragma unroll
        for (int nf = 0; nf < 4; ++nf) {
            const int col = wc + nf * 16 + (l & 15);
            float v[4];
            #pragma unroll
            for (int rr = 0; rr < 4; ++rr)
                v[rr] = accH[mf][nf][rr] + accM[mf][nf][rr] * MS;

            if (MODE == 0) {
                const float bb = bias[bn + col];
                #pragma unroll
                for (int rr = 0; rr < 4; ++rr)
                    C[(size_t)(bm + row0 + rr) * ldc + (bn + col)] = v[rr] + bb;
            } else if (MODE == 2) {
                #pragma unroll
                for (int rr = 0; rr < 4; ++rr) {
                    float* cp = &C[(size_t)(bm + row0 + rr) * ldc + (bn + col)];
                    *cp = *cp + v[rr];
                }
            } else {
                const size_t fu = (size_t)(bn + col);
                const size_t fd0 = (size_t)(fdBase + bm + row0);
                int m[4];
                if (flag == 1) {
                    const int4 mm = *(const int4*)((const int*)conn +
                        (size_t)upIdx * F_DIM * F_DIM + fu * F_DIM + fd0);
                    m[0] = mm.x; m[1] = mm.y; m[2] = mm.z; m[3] = mm.w;
                } else if (flag == 0) {
                    const uchar4 mm = *(const uchar4*)(conn +
                        (size_t)upIdx * F_DIM * F_DIM + fu * F_DIM + fd0);
                    m[0] = mm.x; m[1] = mm.y; m[2] = mm.z; m[3] = mm.w;
                } else if (flag == 2) {
                    const long long* pp = (const long long*)conn +
                        (size_t)upIdx * F_DIM * F_DIM + fu * F_DIM + fd0;
                    m[0] = (int)pp[0]; m[1] = (int)pp[1];
                    m[2] = (int)pp[2]; m[3] = (int)pp[3];
                } else {
                    const float4 mm = *(const float4*)((const float*)conn +
                        (size_t)upIdx * F_DIM * F_DIM + fu * F_DIM + fd0);
                    m[0] = mm.x != 0.f; m[1] = mm.y != 0.f;
                    m[2] = mm.z != 0.f; m[3] = mm.w != 0.f;
                }
                // packed write: row fd, k=fu -> fd*2F + (fu>>5)*64 + (fu&31)
                const size_t kblk = (fu >> 5) * 64 + (fu & 31);
                #pragma unroll
                for (int rr = 0; rr < 4; ++rr) {
                    const float vv = m[rr] ? v[rr] : 0.f;
                    f16 hh, ll;
                    split_f32(vv, hh, ll);
                    const size_t o = (size_t)(bm + row0 + rr) * (2 * F_DIM) + kblk;
                    Vp[o] = hh; Vp[o + 32] = ll;
                }
            }
        }
    }
}

// elementwise split into packed layout: row r of K -> 2K f16, blocks of
// [32 h | 32 l]. 8 contiguous k per thread (stay within one 32-block).
__global__ __launch_bounds__(256)
void split_kernel(const float* __restrict__ src, f16* __restrict__ dst,
                  size_t n, int K)
{
    const size_t e = ((size_t)blockIdx.x * 256 + threadIdx.x) * 8;
    if (e >= n) return;
    const size_t r = e / (size_t)K;
    const int k = (int)(e - r * (size_t)K);
    const float4 a = *(const float4*)(src + e);
    const float4 b = *(const float4*)(src + e + 4);
    f16 hv[8], lv[8];
    const float s[8] = {a.x, a.y, a.z, a.w, b.x, b.y, b.z, b.w};
    #pragma unroll
    for (int i = 0; i < 8; ++i) split_f32(s[i], hv[i], lv[i]);
    const size_t base = r * (size_t)(2 * K) + (size_t)((k >> 5) * 64 + (k & 31));
    *(f16x8*)(dst + base)      = *(const f16x8*)hv;
    *(f16x8*)(dst + base + 32) = *(const f16x8*)lv;
}

// W_enc [768][8192] -> packed W_encT rows f (K=768); reads coalesced along f
__global__ __launch_bounds__(256)
void transpose_split_kernel(const float* __restrict__ W, f16* __restrict__ dst)
{
    const int f = blockIdx.x * 256 + threadIdx.x;
    for (int dc = 0; dc < D_DIM / 8; ++dc) {
        const int k = dc * 8;
        f16 hv[8], lv[8];
        #pragma unroll
        for (int j = 0; j < 8; ++j)
            split_f32(W[(size_t)(k + j) * F_DIM + f], hv[j], lv[j]);
        const size_t base = (size_t)f * (2 * D_DIM) + (k >> 5) * 64 + (k & 31);
        *(f16x8*)(dst + base)      = *(const f16x8*)hv;
        *(f16x8*)(dst + base + 32) = *(const f16x8*)lv;
    }
}

// conn_mask storage-layout detection: 0=u8, 1=i32, 2=i64, 3=f32
__global__ void detect_kernel(const int* __restrict__ conn, int* __restrict__ flag)
{
    __shared__ int not01, notf01, odd_nz;
    if (threadIdx.x == 0) { not01 = 0; notf01 = 0; odd_nz = 0; }
    __syncthreads();
    const int4 v = ((const int4*)conn)[threadIdx.x];
    const unsigned a[4] = {(unsigned)v.x, (unsigned)v.y,
                           (unsigned)v.z, (unsigned)v.w};
    int l_not01 = 0, l_notf = 0;
    #pragma unroll
    for (int i = 0; i < 4; ++i) {
        if (a[i] > 1u) l_not01 = 1;
        if (a[i] != 0u && a[i] != 0x3F800000u) l_notf = 1;
    }
    if (l_not01) atomicOr(&not01, 1);
    if (l_notf)  atomicOr(&notf01, 1);
    if (a[1] | a[3]) atomicOr(&odd_nz, 1);
    __syncthreads();
    if (threadIdx.x == 0) {
        int f;
        if (!not01)        f = odd_nz ? 1 : 2;
        else if (!notf01)  f = 3;
        else               f = 0;
        *flag = f;
    }
}

__global__ void bias2_kernel(const float* __restrict__ W_enc,
                             const float* __restrict__ b_enc,
                             const float* __restrict__ up_b_dec,
                             int nup, float* __restrict__ bias2)
{
    const int g = blockIdx.x * 256 + threadIdx.x;
    if (g >= F_DIM) return;
    float s = b_enc[g];
    for (int d = 0; d < D_DIM; ++d) {
        float ub = 0.f;
        for (int i = 0; i < nup; ++i) ub += up_b_dec[i * D_DIM + d];
        s = __builtin_fmaf(ub, W_enc[(size_t)d * F_DIM + g], s);
    }
    bias2[g] = s;
}

// exact radix top-k (ties -> lowest index), relu, sparse decode
__global__ __launch_bounds__(256)
void topk_decode_kernel(const float* __restrict__ approx,
                        const float* __restrict__ W_dec,
                        const float* __restrict__ b_dec,
                        const int* __restrict__ kptr,
                        float* __restrict__ out)
{
    __shared__ unsigned keys[F_DIM];
    __shared__ int hist[256];
    __shared__ unsigned sh_prefix;
    __shared__ int sh_need;
    __shared__ int sel_cnt, eq_cnt;
    __shared__ int sidx[128];
    __shared__ float sval[128];
    __shared__ int eqidx[1024];

    const int tid = threadIdx.x;
    const int row = blockIdx.x;
    const int k = *kptr;
    const float* arow = approx + (size_t)row * F_DIM;

    for (int j = tid; j < F_DIM; j += 256) {
        unsigned u = __float_as_uint(arow[j]);
        u = (u & 0x80000000u) ? ~u : (u | 0x80000000u);
        keys[j] = u;
    }
    if (tid == 0) { sh_prefix = 0u; sh_need = k; sel_cnt = 0; eq_cnt = 0; }
    __syncthreads();

    for (int shift = 24; shift >= 0; shift -= 8) {
        if (tid < 256) hist[tid] = 0;
        __syncthreads();
        const unsigned pfx = sh_prefix;
        for (int j = tid; j < F_DIM; j += 256) {
            const unsigned u = keys[j];
            const bool match =
                (shift == 24) || ((u >> (shift + 8)) == (pfx >> (shift + 8)));
            if (match) atomicAdd(&hist[(u >> shift) & 255], 1);
        }
        __syncthreads();
        if (tid == 0) {
            int need = sh_need;
            for (int b = 255; b >= 0; --b) {
                const int c = hist[b];
                if (c >= need) {
                    sh_prefix = pfx | ((unsigned)b << shift);
                    sh_need = need;
                    break;
                }
                need -= c;
            }
        }
        __syncthreads();
    }
    const unsigned T = sh_prefix;
    const int r = sh_need;

    for (int j = tid; j < F_DIM; j += 256) {
        const unsigned u = keys[j];
        if (u > T) {
            const int p = atomicAdd(&sel_cnt, 1);
            sidx[p] = j;
        } else if (u == T) {
            const int p = atomicAdd(&eq_cnt, 1);
            if (p < 1024) eqidx[p] = j;
        }
    }
    __syncthreads();

    if (tid == 0) {
        const int m = sel_cnt;
        const int e = eq_cnt < 1024 ? eq_cnt : 1024;
        for (int t2 = 0; t2 < r; ++t2) {
            int best = 0x7FFFFFFF, bi = -1;
            for (int q = 0; q < e; ++q) {
                const int v = eqidx[q];
                if (v >= 0 && v < best) { best = v; bi = q; }
            }
            if (bi >= 0) { eqidx[bi] = -1; sidx[m + t2] = best; }
        }
        sel_cnt = m + r;
        const int n = sel_cnt;
        for (int a2 = 1; a2 < n; ++a2) {
            const int v = sidx[a2];
            int b2 = a2 - 1;
            while (b2 >= 0 && sidx[b2] > v) { sidx[b2 + 1] = sidx[b2]; --b2; }
            sidx[b2 + 1] = v;
        }
    }
    __syncthreads();

    const int total = sel_cnt;
    for (int j = tid; j < total; j += 256) {
        const float v = arow[sidx[j]];
        sval[j] = v > 0.f ? v : 0.f;
    }
    __syncthreads();

    float acc0 = b_dec[tid];
    float acc1 = b_dec[tid + 256];
    float acc2 = b_dec[tid + 512];
    for (int j = 0; j < total; ++j) {
        const float v = sval[j];
        const float* wv = W_dec + (size_t)sidx[j] * D_DIM;
        acc0 = __builtin_fmaf(v, wv[tid],       acc0);
        acc1 = __builtin_fmaf(v, wv[tid + 256], acc1);
        acc2 = __builtin_fmaf(v, wv[tid + 512], acc2);
    }
    float* orow = out + (size_t)row * D_DIM;
    orow[tid] = acc0;
    orow[tid + 256] = acc1;
    orow[tid + 512] = acc2;
}

extern "C" void kernel_launch(void* const* d_in, const int* in_sizes, int n_in,
                              void* d_out, int out_size, void* d_ws, size_t ws_size,
                              hipStream_t stream)
{
    const float* x         = (const float*)d_in[1];
    const float* up_feats  = (const float*)d_in[2];
    const float* W_enc     = (const float*)d_in[3];
    const float* b_enc     = (const float*)d_in[4];
    const float* W_dec     = (const float*)d_in[5];
    const float* b_dec     = (const float*)d_in[6];
    const float* up_W_dec  = (const float*)d_in[7];
    const float* up_b_dec  = (const float*)d_in[8];
    const unsigned char* conn = (const unsigned char*)d_in[9];
    const int* kptr        = (const int*)d_in[10];

    const int BS  = in_sizes[1] / D_DIM;    // 2048
    const int NUP = in_sizes[8] / D_DIM;    // 3

    char* ws = (char*)d_ws;
    size_t off = 0;
    auto alloc = [&](size_t bytes) -> char* {
        off = (off + 255) & ~(size_t)255;
        char* p = ws + off; off += bytes; return p;
    };
    float* approx = (float*)alloc((size_t)BS * F_DIM * 4);
    float* bias2  = (float*)alloc(F_DIM * 4);
    int*   flag   = (int*)alloc(256);
    // packed arrays: logical n elems -> 2n f16 = 4n bytes
    f16* xp   = (f16*)alloc((size_t)BS * D_DIM * 4);
    f16* Wtp  = (f16*)alloc((size_t)F_DIM * D_DIM * 4);
    f16* uwdp = (f16*)alloc((size_t)NUP * F_DIM * D_DIM * 4);
    f16* ufp  = (f16*)alloc((size_t)NUP * BS * F_DIM * 4);

    off = (off + 255) & ~(size_t)255;
    const size_t rem = (ws_size > off) ? ws_size - off : 0;
    int FC = (int)((rem / ((size_t)F_DIM * 4)) / 128 * 128);
    if (FC > F_DIM) FC = F_DIM;
    if (FC < 128) FC = 128;   // ws observed ~3.2GB -> FC = 8192
    f16* vp = (f16*)alloc((size_t)FC * F_DIM * 4);

    detect_kernel<<<1, 256, 0, stream>>>((const int*)conn, flag);
    bias2_kernel<<<F_DIM / 256, 256, 0, stream>>>(W_enc, b_enc, up_b_dec, NUP, bias2);

    split_kernel<<<(unsigned)((size_t)BS * D_DIM / 2048), 256, 0, stream>>>(
        x, xp, (size_t)BS * D_DIM, D_DIM);
    split_kernel<<<(unsigned)((size_t)NUP * F_DIM * D_DIM / 2048), 256, 0, stream>>>(
        up_W_dec, uwdp, (size_t)NUP * F_DIM * D_DIM, D_DIM);
    split_kernel<<<(unsigned)((size_t)NUP * BS * F_DIM / 2048), 256, 0, stream>>>(
        up_feats, ufp, (size_t)NUP * BS * F_DIM, F_DIM);
    transpose_split_kernel<<<F_DIM / 256, 256, 0, stream>>>(W_enc, Wtp);

    // G0: approx = x @ W_enc + bias2
    mfma_gemm<0><<<dim3(F_DIM / BMN, BS / BMN), 256, 0, stream>>>(
        xp, Wtp, approx, F_DIM, nullptr, bias2,
        nullptr, 0, flag, D_DIM, 0);

    for (int i = 0; i < NUP; ++i) {
        for (int fc = 0; fc < F_DIM; fc += FC) {
            const int chunk = (F_DIM - fc) < FC ? (F_DIM - fc) : FC;
            // G1: virtT[fd in chunk][fu] = (W_encT @ up_W_dec[i]^T) * maskT
            mfma_gemm<1><<<dim3(F_DIM / BMN, chunk / BMN), 256, 0, stream>>>(
                Wtp + (size_t)fc * (2 * D_DIM),
                uwdp + (size_t)i * F_DIM * (2 * D_DIM),
                nullptr, 0, vp, nullptr,
                conn, i, flag, D_DIM, fc);
            // G2: approx[:, fc:fc+chunk] += up_feats[i] @ virt  (K = 8192 fu)
            mfma_gemm<2><<<dim3(chunk / BMN, BS / BMN), 256, 0, stream>>>(
                ufp + (size_t)i * BS * (2 * F_DIM),
                vp,
                approx + fc, F_DIM, nullptr, nullptr,
                nullptr, 0, flag, F_DIM, 0);
        }
    }

    topk_decode_kernel<<<BS, 256, 0, stream>>>(
        approx, W_dec, b_dec, kptr, (float*)d_out);
}